// Round 4
// baseline (4713.015 us; speedup 1.0000x reference)
//
#include <hip/hip_runtime.h>

#define DI __device__ __forceinline__
#define NSAMP 65536

DI float frcp(float x){ return __builtin_amdgcn_rcpf(x); }
DI float frsq(float x){ return __builtin_amdgcn_rsqf(x); }
DI float sigmf(float x){ return frcp(1.f + __expf(-x)); }
DI float tanhf_(float x){ return 1.f - 2.f*frcp(__expf(2.f*x) + 1.f); }

struct Params {
  const float* __restrict__ x;
  const float* __restrict__ xT;    // SoA packed features [320][NSAMP] (ws)
  const float* __restrict__ w1ft;  // W1f transposed [108][32] (ws tail)
  const float* __restrict__ Wih0; const float* __restrict__ Whh0;
  const float* __restrict__ bih0; const float* __restrict__ bhh0;
  const float* __restrict__ Wih1; const float* __restrict__ Whh1;
  const float* __restrict__ bih1; const float* __restrict__ bhh1;
  const float* __restrict__ fcW;  const float* __restrict__ fcb;
  const float* __restrict__ W2;   const float* __restrict__ b2;
  const float* __restrict__ g2;   const float* __restrict__ be2;
  const float* __restrict__ W3;   const float* __restrict__ b3;
  const float* __restrict__ g3;   const float* __restrict__ be3;
  const float* __restrict__ W1f;  const float* __restrict__ b1f;
  const float* __restrict__ g1f;  const float* __restrict__ be1f;
  const float* __restrict__ W2f;  const float* __restrict__ b2f;
  const float* __restrict__ g2f;  const float* __restrict__ be2f;
  const float* __restrict__ W3f;  const float* __restrict__ b3f;
  const float* __restrict__ g3f;  const float* __restrict__ be3f;
  float* __restrict__ out;
};

template<bool SOA>
DI float ldcsi(const float* __restrict__ base, int b, int r, int c){
  if constexpr(SOA) return base[(size_t)(r*102 + c)*NSAMP + b];
  else              return base[(size_t)b*348 + r*116 + 1 + c];
}
template<bool SOA>
DI float ldpos(const float* __restrict__ base, int b, int k){
  if constexpr(SOA) return base[(size_t)(306 + k)*NSAMP + b];
  else              return base[(size_t)b*348 + 220 + k];
}

// ---------- pack kernel: x (AoS) -> xT (SoA), plus W1f transpose ----------
__global__ __launch_bounds__(256,1) void pack_kernel(const float* __restrict__ x,
                                                     float* __restrict__ xT,
                                                     const float* __restrict__ W1f,
                                                     float* __restrict__ w1ft){
  __shared__ float s[64*349];
  const int b0 = blockIdx.x*64;
  const float4* src = reinterpret_cast<const float4*>(x + (size_t)b0*348);
  for(int i=threadIdx.x; i<64*87; i+=256){
    float4 v = src[i];
    int smp = i/87; int off = (i - smp*87)*4;
    float* d = &s[smp*349 + off];
    d[0]=v.x; d[1]=v.y; d[2]=v.z; d[3]=v.w;
  }
  __syncthreads();
  for(int i=threadIdx.x; i<320*64; i+=256){
    int f = i>>6; int sI = i&63;
    int off;
    if(f < 306){ int r = f/102; off = r*14 + 1 + f; }
    else if(f < 318) off = 220 + (f-306);
    else off = 0;
    xT[(size_t)f*NSAMP + b0 + sI] = s[sI*349 + off];
  }
  if(blockIdx.x == 0){
    for(int i=threadIdx.x; i<108*32; i+=256){
      int w = i>>5, j = i&31;
      w1ft[w*32 + j] = W1f[j*108 + w];
    }
  }
}

// quad allgather: each lane of a 4-lane group holds 8 values (block q*8..q*8+7);
// produce full 32 in every lane. Static register indices throughout.
DI void allgather32(const float* mine8, float* full32, int q){
  const bool q1 = (q & 1) != 0;
  const bool q2 = (q & 2) != 0;
  float a[16];
  #pragma unroll
  for(int i=0;i<8;i++){
    float o = __shfl_xor(mine8[i], 1);
    a[i]    = q1 ? o : mine8[i];
    a[8+i]  = q1 ? mine8[i] : o;
  }
  #pragma unroll
  for(int i=0;i<16;i++){
    float o = __shfl_xor(a[i], 2);
    full32[i]    = q2 ? o : a[i];
    full32[16+i] = q2 ? a[i] : o;
  }
}
DI float qreduce(float v){
  v += __shfl_xor(v, 1);
  v += __shfl_xor(v, 2);
  return v;
}

template<int IN>
DI void lstm_step8(const float* __restrict__ Wih, const float* __restrict__ Whh,
                   const float* __restrict__ bih, const float* __restrict__ bhh,
                   int J0, const float* xin, const float* hin32,
                   float* c8, float* h8){
  #pragma unroll
  for(int jj=0;jj<8;jj++){
    const int j = J0 + jj;
    float ai = bih[j]    + bhh[j];
    float af = bih[32+j] + bhh[32+j];
    float ag = bih[64+j] + bhh[64+j];
    float ao = bih[96+j] + bhh[96+j];
    #pragma unroll
    for(int k=0;k<IN;k++){
      float xv = xin[k];
      ai += xv*Wih[j*IN+k];
      af += xv*Wih[(32+j)*IN+k];
      ag += xv*Wih[(64+j)*IN+k];
      ao += xv*Wih[(96+j)*IN+k];
    }
    #pragma unroll
    for(int k=0;k<32;k++){
      float hv = hin32[k];
      ai += hv*Whh[j*32+k];
      af += hv*Whh[(32+j)*32+k];
      ag += hv*Whh[(64+j)*32+k];
      ao += hv*Whh[(96+j)*32+k];
    }
    float cc = sigmf(af)*c8[jj] + sigmf(ai)*tanhf_(ag);
    c8[jj] = cc;
    h8[jj] = sigmf(ao)*tanhf_(cc);
  }
}

// 4 threads (a lane quad) cooperate on one sample. 128 thr = 32 samples/block.
// launch_bounds(128,2): 256-VGPR budget -> no spill (R3's (128,3)=170 cap
// caused a catastrophic spill: VGPR 84, 10.2 GB scratch traffic).
template<bool SOA>
__global__ __launch_bounds__(128,2) void csnet_main(Params p){
  const int tid  = threadIdx.x;
  const int q    = tid & 3;
  const int sloc = tid >> 2;
  const int b    = blockIdx.x*32 + sloc;
  const float* __restrict__ xb = SOA ? p.xT : p.x;
  __shared__ float sbuf[32*103];
  float* my = &sbuf[sloc*103];
  const int J0    = q*8;
  const int cbase = q*26;
  const int ncol  = (q==3) ? 24 : 26;

  // ---------------- LSTM (2 layers, 4 steps), 8 units/thread ----------------
  float h0f[32], h1f[32], c0[8], c1[8];
  #pragma unroll
  for(int j=0;j<32;j++){ h0f[j]=0.f; h1f[j]=0.f; }
  #pragma unroll
  for(int j=0;j<8;j++){ c0[j]=0.f; c1[j]=0.f; }
  #pragma unroll 1
  for(int t=0;t<4;t++){
    float xt[3];
    #pragma unroll
    for(int d=0;d<3;d++) xt[d] = ldpos<SOA>(xb, b, t*3+d);
    float h8a[8], h8b[8];
    lstm_step8<3 >(p.Wih0,p.Whh0,p.bih0,p.bhh0, J0, xt,  h0f, c0, h8a);
    allgather32(h8a, h0f, q);
    lstm_step8<32>(p.Wih1,p.Whh1,p.bih1,p.bhh1, J0, h0f, h1f, c1, h8b);
    allgather32(h8b, h1f, q);
  }
  float pp[3], vel[3];
  #pragma unroll
  for(int d=0;d<3;d++){
    float a = p.fcb[d];
    #pragma unroll
    for(int j=0;j<32;j++) a += h1f[j]*p.fcW[d*32+j];
    pp[d]  = a;
    vel[d] = (a - ldpos<SOA>(xb, b, 9+d))*10.f;
  }

  // ---------------- conv2 pass 1: LN stats, 26 cols/thread ----------------
  float s1 = 0.f, s2 = 0.f;
  {
    float u0[3],u1[3],u2[3],u3[3],u4[3];
    #pragma unroll
    for(int r=0;r<3;r++){
      int pc;
      pc = cbase-2; u0[r] = (pc>=0) ? ldcsi<SOA>(xb,b,r,pc<0?0:pc) : 0.f;
      pc = cbase-1; u1[r] = (pc>=0) ? ldcsi<SOA>(xb,b,r,pc<0?0:pc) : 0.f;
      u2[r] = ldcsi<SOA>(xb,b,r,cbase);
      u3[r] = ldcsi<SOA>(xb,b,r,cbase+1);
      u4[r] = ldcsi<SOA>(xb,b,r,cbase+2);
    }
    #pragma unroll 2
    for(int i=0;i<26;i++){
      float msk = (q==3 && i>=24) ? 0.f : 1.f;
      #pragma unroll
      for(int o=0;o<4;o++){
        const float* Wo = &p.W2[o*15];
        float s = p.b2[o];
        #pragma unroll
        for(int r=0;r<3;r++)
          s += u0[r]*Wo[r*5+0]+u1[r]*Wo[r*5+1]+u2[r]*Wo[r*5+2]+u3[r]*Wo[r*5+3]+u4[r]*Wo[r*5+4];
        s1 += msk*s; s2 += msk*s*s;
      }
      int pnext = cbase + i + 3;
      #pragma unroll
      for(int r=0;r<3;r++){
        float nv = ldcsi<SOA>(xb,b,r,pnext);
        nv = (pnext <= 101) ? nv : 0.f;
        u0[r]=u1[r]; u1[r]=u2[r]; u2[r]=u3[r]; u3[r]=u4[r]; u4[r]=nv;
      }
    }
  }
  float m2  = qreduce(s1)*(1.f/408.f);
  float va2 = qreduce(s2)*(1.f/408.f) - m2*m2;
  float rs2 = frsq(va2 + 1e-5f);

  // ---------- conv2 pass 2 (recompute) + LN/relu + cv3 -> my[w] ----------
  float w3v[4];
  #pragma unroll
  for(int o=0;o<4;o++) w3v[o] = p.W3[o];
  float b3v = p.b3[0];
  float s31=0.f, s32=0.f;
  {
    float u0[3],u1[3],u2[3],u3[3],u4[3];
    #pragma unroll
    for(int r=0;r<3;r++){
      int pc;
      pc = cbase-2; u0[r] = (pc>=0) ? ldcsi<SOA>(xb,b,r,pc<0?0:pc) : 0.f;
      pc = cbase-1; u1[r] = (pc>=0) ? ldcsi<SOA>(xb,b,r,pc<0?0:pc) : 0.f;
      u2[r] = ldcsi<SOA>(xb,b,r,cbase);
      u3[r] = ldcsi<SOA>(xb,b,r,cbase+1);
      u4[r] = ldcsi<SOA>(xb,b,r,cbase+2);
    }
    #pragma unroll 2
    for(int i=0;i<26;i++){
      const int w = cbase + i;
      float msk = (q==3 && i>=24) ? 0.f : 1.f;
      float o3 = b3v;
      #pragma unroll
      for(int o=0;o<4;o++){
        const float* Wo = &p.W2[o*15];
        float s = p.b2[o];
        #pragma unroll
        for(int r=0;r<3;r++)
          s += u0[r]*Wo[r*5+0]+u1[r]*Wo[r*5+1]+u2[r]*Wo[r*5+2]+u3[r]*Wo[r*5+3]+u4[r]*Wo[r*5+4];
        int wc = (w <= 101) ? w : 101;
        float nv = (s - m2)*rs2*p.g2[o*102+wc] + p.be2[o*102+wc];
        o3 += fmaxf(nv, 0.f)*w3v[o];
      }
      s31 += msk*o3; s32 += msk*o3*o3;
      if(i < ncol) my[w] = o3;
      int pnext = cbase + i + 3;
      #pragma unroll
      for(int r=0;r<3;r++){
        float nv = ldcsi<SOA>(xb,b,r,pnext);
        nv = (pnext <= 101) ? nv : 0.f;
        u0[r]=u1[r]; u1[r]=u2[r]; u2[r]=u3[r]; u3[r]=u4[r]; u4[r]=nv;
      }
    }
  }
  float m3  = qreduce(s31)*(1.f/102.f);
  float va3 = qreduce(s32)*(1.f/102.f) - m3*m3;
  float rs3 = frsq(va3 + 1e-5f);

  // ---------------- f1: 108 -> 32 (8 outputs/thread), LN, relu ----------------
  float a1[8];
  #pragma unroll
  for(int jj=0;jj<8;jj++) a1[jj] = p.b1f[J0+jj];
  #pragma unroll 2
  for(int w=0; w<102; ++w){
    float v = (my[w]-m3)*rs3*p.g3[w] + p.be3[w];
    v = fmaxf(v, 0.f);
    const float* wr = SOA ? &p.w1ft[w*32+J0] : nullptr;
    #pragma unroll
    for(int jj=0;jj<8;jj++)
      a1[jj] += v * (SOA ? wr[jj] : p.W1f[(J0+jj)*108+w]);
  }
  #pragma unroll
  for(int d=0;d<3;d++){
    #pragma unroll
    for(int jj=0;jj<8;jj++){
      a1[jj] += pp[d]  * (SOA ? p.w1ft[(102+d)*32+J0+jj] : p.W1f[(J0+jj)*108+102+d]);
      a1[jj] += vel[d] * (SOA ? p.w1ft[(105+d)*32+J0+jj] : p.W1f[(J0+jj)*108+105+d]);
    }
  }
  {
    float s=0.f, qq=0.f;
    #pragma unroll
    for(int jj=0;jj<8;jj++){ s += a1[jj]; qq += a1[jj]*a1[jj]; }
    float m  = qreduce(s)*(1.f/32.f);
    float va = qreduce(qq)*(1.f/32.f) - m*m;
    float rs = frsq(va + 1e-5f);
    #pragma unroll
    for(int jj=0;jj<8;jj++)
      a1[jj] = fmaxf((a1[jj]-m)*rs*p.g1f[J0+jj] + p.be1f[J0+jj], 0.f);
  }

  // ---------------- f2: 32 -> 32 (8 outputs/thread), LN, relu ----------------
  float a1f[32];
  allgather32(a1, a1f, q);
  float a2[8];
  #pragma unroll
  for(int jj=0;jj<8;jj++){
    const int j = J0 + jj;
    float a = p.b2f[j];
    #pragma unroll
    for(int k=0;k<32;k++) a += a1f[k]*p.W2f[j*32+k];
    a2[jj] = a;
  }
  {
    float s=0.f, qq=0.f;
    #pragma unroll
    for(int jj=0;jj<8;jj++){ s += a2[jj]; qq += a2[jj]*a2[jj]; }
    float m  = qreduce(s)*(1.f/32.f);
    float va = qreduce(qq)*(1.f/32.f) - m*m;
    float rs = frsq(va + 1e-5f);
    #pragma unroll
    for(int jj=0;jj<8;jj++)
      a2[jj] = fmaxf((a2[jj]-m)*rs*p.g2f[J0+jj] + p.be2f[J0+jj], 0.f);
  }

  // ---------------- f3: 32 -> 102 (26 cols/thread), LN, sigmoid ----------------
  float a2f[32];
  allgather32(a2, a2f, q);
  float fw[26];
  float t1=0.f, t2=0.f;
  #pragma unroll
  for(int i=0;i<26;i++){
    const int w  = cbase + i;
    const int wc = (w <= 101) ? w : 101;
    float a = p.b3f[wc];
    #pragma unroll
    for(int j=0;j<32;j++) a += a2f[j]*p.W3f[wc*32+j];
    float msk = (q==3 && i>=24) ? 0.f : 1.f;
    t1 += msk*a; t2 += msk*a*a;
    fw[i] = a;
  }
  float mf  = qreduce(t1)*(1.f/102.f);
  float vaf = qreduce(t2)*(1.f/102.f) - mf*mf;
  float rsf = frsq(vaf + 1e-5f);
  #pragma unroll
  for(int i=0;i<26;i++){
    const int w = cbase + i;
    if(i < ncol){
      float u = (fw[i]-mf)*rsf*p.g3f[w] + p.be3f[w];
      my[w] = sigmf(u);
    }
  }
  __syncthreads();

  // ---------------- coalesced float4 store: 3264 floats/block ----------------
  float* op = p.out + (size_t)blockIdx.x*3264;
  #pragma unroll 1
  for(int m=0;m<7;m++){
    int i4 = tid + 128*m;
    if(i4 < 816){
      int i0 = i4*4;
      float4 v;
      #pragma unroll
      for(int e=0;e<4;e++){
        int idx = i0 + e;
        int sm = idx/102;
        int wd = idx - sm*102;
        ((float*)&v)[e] = sbuf[sm*103 + wd];
      }
      *reinterpret_cast<float4*>(op + i0) = v;
    }
  }
}

extern "C" void kernel_launch(void* const* d_in, const int* in_sizes, int n_in,
                              void* d_out, int out_size, void* d_ws, size_t ws_size,
                              hipStream_t stream) {
  (void)in_sizes; (void)n_in; (void)out_size;
  Params p;
  p.x    = (const float*)d_in[0];
  p.Wih0 = (const float*)d_in[1];  p.Whh0 = (const float*)d_in[2];
  p.bih0 = (const float*)d_in[3];  p.bhh0 = (const float*)d_in[4];
  p.Wih1 = (const float*)d_in[5];  p.Whh1 = (const float*)d_in[6];
  p.bih1 = (const float*)d_in[7];  p.bhh1 = (const float*)d_in[8];
  p.fcW  = (const float*)d_in[9];  p.fcb  = (const float*)d_in[10];
  p.W2   = (const float*)d_in[11]; p.b2   = (const float*)d_in[12];
  p.g2   = (const float*)d_in[13]; p.be2  = (const float*)d_in[14];
  p.W3   = (const float*)d_in[15]; p.b3   = (const float*)d_in[16];
  p.g3   = (const float*)d_in[17]; p.be3  = (const float*)d_in[18];
  p.W1f  = (const float*)d_in[19]; p.b1f  = (const float*)d_in[20];
  p.g1f  = (const float*)d_in[21]; p.be1f = (const float*)d_in[22];
  p.W2f  = (const float*)d_in[23]; p.b2f  = (const float*)d_in[24];
  p.g2f  = (const float*)d_in[25]; p.be2f = (const float*)d_in[26];
  p.W3f  = (const float*)d_in[27]; p.b3f  = (const float*)d_in[28];
  p.g3f  = (const float*)d_in[29]; p.be3f = (const float*)d_in[30];
  p.out  = (float*)d_out;

  const size_t need = ((size_t)320*NSAMP + 108*32)*sizeof(float);
  if(ws_size >= need){
    float* xT   = (float*)d_ws;
    float* w1ft = xT + (size_t)320*NSAMP;
    p.xT = xT; p.w1ft = w1ft;
    pack_kernel<<<NSAMP/64, 256, 0, stream>>>(p.x, xT, p.W1f, w1ft);
    csnet_main<true><<<NSAMP/32, 128, 0, stream>>>(p);
  } else {
    p.xT = nullptr; p.w1ft = nullptr;
    csnet_main<false><<<NSAMP/32, 128, 0, stream>>>(p);
  }
}

// Round 5
// 324.795 us; speedup vs baseline: 14.5108x; 14.5108x over previous
//
#include <hip/hip_runtime.h>

#define DI __device__ __forceinline__
#define NSAMP 65536

typedef __attribute__((ext_vector_type(4))) float f32x4;
typedef __attribute__((ext_vector_type(8))) short short8;

DI float frcp(float x){ return __builtin_amdgcn_rcpf(x); }
DI float frsq(float x){ return __builtin_amdgcn_rsqf(x); }
DI float sigmf(float x){ return frcp(1.f + __expf(-x)); }
DI float tanhf_(float x){ return 1.f - 2.f*frcp(__expf(2.f*x) + 1.f); }
DI unsigned short f2bf(float f){                 // RNE float->bf16
  unsigned u = __float_as_uint(f);
  return (unsigned short)((u + 0x7FFFu + ((u>>16)&1u)) >> 16);
}

struct Params {
  const float* __restrict__ x;
  const float* __restrict__ xT;
  const float* __restrict__ w1ft;
  const float* __restrict__ pv;    // [6][NSAMP]: pp0..2, vel0..2
  const float* __restrict__ Wih0; const float* __restrict__ Whh0;
  const float* __restrict__ bih0; const float* __restrict__ bhh0;
  const float* __restrict__ Wih1; const float* __restrict__ Whh1;
  const float* __restrict__ bih1; const float* __restrict__ bhh1;
  const float* __restrict__ fcW;  const float* __restrict__ fcb;
  const float* __restrict__ W2;   const float* __restrict__ b2;
  const float* __restrict__ g2;   const float* __restrict__ be2;
  const float* __restrict__ W3;   const float* __restrict__ b3;
  const float* __restrict__ g3;   const float* __restrict__ be3;
  const float* __restrict__ W1f;  const float* __restrict__ b1f;
  const float* __restrict__ g1f;  const float* __restrict__ be1f;
  const float* __restrict__ W2f;  const float* __restrict__ b2f;
  const float* __restrict__ g2f;  const float* __restrict__ be2f;
  const float* __restrict__ W3f;  const float* __restrict__ b3f;
  const float* __restrict__ g3f;  const float* __restrict__ be3f;
  float* __restrict__ out;
};

DI float ldcsi(const float* __restrict__ xT, int b, int r, int c){
  return xT[(size_t)(r*102 + c)*NSAMP + b];
}

// ---------- pack: x (AoS) -> xT (SoA), W1f transpose ----------
__global__ __launch_bounds__(256,1) void pack_kernel(const float* __restrict__ x,
                                                     float* __restrict__ xT,
                                                     const float* __restrict__ W1f,
                                                     float* __restrict__ w1ft){
  __shared__ float s[64*349];
  const int b0 = blockIdx.x*64;
  const float4* src = reinterpret_cast<const float4*>(x + (size_t)b0*348);
  for(int i=threadIdx.x; i<64*87; i+=256){
    float4 v = src[i];
    int smp = i/87; int off = (i - smp*87)*4;
    float* d = &s[smp*349 + off];
    d[0]=v.x; d[1]=v.y; d[2]=v.z; d[3]=v.w;
  }
  __syncthreads();
  for(int i=threadIdx.x; i<320*64; i+=256){
    int f = i>>6; int sI = i&63;
    int off;
    if(f < 306){ int r = f/102; off = r*14 + 1 + f; }
    else if(f < 318) off = 220 + (f-306);
    else off = 0;
    xT[(size_t)f*NSAMP + b0 + sI] = s[sI*349 + off];
  }
  if(blockIdx.x == 0){
    for(int i=threadIdx.x; i<108*32; i+=256){
      int w = i>>5, j = i&31;
      w1ft[w*32 + j] = W1f[j*108 + w];
    }
  }
}

// ---------- prep: weight B-fragments (bf16) + bias sums ----------
// B-frag layout for mfma_f32_16x16x32_bf16: lane l holds B[k][n] with
// n = 16*tile + (l&15); elems j=0..3 -> k=4*(l>>4)+j, j=4..7 -> k=16+4*(l>>4)+j.
// mats: 0=Whh0, 1=Wih1, 2=Whh1 (each [128][32] = W[n][k]); 3=Wih0 padded K3->32.
__global__ __launch_bounds__(256,1) void prep_kernel(
    const float* __restrict__ Whh0, const float* __restrict__ Wih1,
    const float* __restrict__ Whh1, const float* __restrict__ Wih0,
    const float* __restrict__ bih0, const float* __restrict__ bhh0,
    const float* __restrict__ bih1, const float* __restrict__ bhh1,
    unsigned short* __restrict__ frags, float* __restrict__ bsum){
  const int tid = threadIdx.x;
  if(tid < 64){
    const int l15 = tid & 15, g4 = tid >> 4;
    const float* mats[3] = {Whh0, Wih1, Whh1};
    for(int m=0;m<3;m++){
      for(int t=0;t<8;t++){
        const int n = 16*t + l15;
        unsigned short* dst = &frags[((size_t)(m*8+t)*64 + tid)*8];
        for(int j=0;j<4;j++){
          dst[j]   = f2bf(mats[m][n*32 + 4*g4 + j]);
          dst[4+j] = f2bf(mats[m][n*32 + 16 + 4*g4 + j]);
        }
      }
    }
    for(int t=0;t<8;t++){
      const int n = 16*t + l15;
      unsigned short* dst = &frags[((size_t)(24+t)*64 + tid)*8];
      for(int j=0;j<4;j++){
        int k = 4*g4 + j;
        dst[j]   = (k < 3) ? f2bf(Wih0[n*3 + k]) : (unsigned short)0;
        dst[4+j] = 0;
      }
    }
  } else if(tid < 192){
    int i = tid - 64;
    bsum[i]       = bih0[i] + bhh0[i];
    bsum[128 + i] = bih1[i] + bhh1[i];
  }
}

// A-frag: row m=l&15, k=4*(l>>4)+j (elems 0-3) and 16+4*(l>>4)+j (elems 4-7),
// read from fp32 LDS h-buffer [16][36].
DI short8 mk_afrag(const float* hbase, int l15, int g4){
  const float4* p0 = (const float4*)(hbase + l15*36 + 4*g4);
  const float4* p1 = (const float4*)(hbase + l15*36 + 16 + 4*g4);
  float4 lo = *p0; float4 hi = *p1;
  short8 s;
  s[0]=(short)f2bf(lo.x); s[1]=(short)f2bf(lo.y); s[2]=(short)f2bf(lo.z); s[3]=(short)f2bf(lo.w);
  s[4]=(short)f2bf(hi.x); s[5]=(short)f2bf(hi.y); s[6]=(short)f2bf(hi.z); s[7]=(short)f2bf(hi.w);
  return s;
}

// ---------- LSTM via MFMA: 1 wave = 16 samples ----------
__global__ __launch_bounds__(256,2) void lstm_kernel(
    const float* __restrict__ xT, const unsigned short* __restrict__ frags,
    const float* __restrict__ bsum, const float* __restrict__ fcW,
    const float* __restrict__ fcb, float* __restrict__ pv){
  __shared__ float hb[4][2][16][36];
  const int tid = threadIdx.x;
  const int w = tid >> 6, l = tid & 63;
  const int l15 = l & 15, g4 = l >> 4;
  const int base = blockIdx.x*64 + w*16;

  short8 wf[4][8];
  const short8* fsrc = (const short8*)frags;
  #pragma unroll
  for(int m=0;m<4;m++)
    #pragma unroll
    for(int t=0;t<8;t++) wf[m][t] = fsrc[(m*8+t)*64 + l];

  float bfr[2][8];
  #pragma unroll
  for(int t=0;t<8;t++){
    bfr[0][t] = bsum[16*t + l15];
    bfr[1][t] = bsum[128 + 16*t + l15];
  }

  #pragma unroll
  for(int half=0; half<2; half++)
    #pragma unroll
    for(int r=0;r<4;r++){
      hb[w][0][g4*4+r][l15+16*half] = 0.f;
      hb[w][1][g4*4+r][l15+16*half] = 0.f;
    }
  float c0[8], c1[8];
  #pragma unroll
  for(int i=0;i<8;i++){ c0[i]=0.f; c1[i]=0.f; }

  #pragma unroll 1
  for(int t=0;t<4;t++){
    // x fragment: only lanes g4==0 carry k=0..2
    short8 ax;
    {
      float xv0 = xT[(size_t)(306 + t*3 + 0)*NSAMP + base + l15];
      float xv1 = xT[(size_t)(306 + t*3 + 1)*NSAMP + base + l15];
      float xv2 = xT[(size_t)(306 + t*3 + 2)*NSAMP + base + l15];
      bool gz = (g4 == 0);
      ax[0] = gz ? (short)f2bf(xv0) : (short)0;
      ax[1] = gz ? (short)f2bf(xv1) : (short)0;
      ax[2] = gz ? (short)f2bf(xv2) : (short)0;
      ax[3]=0; ax[4]=0; ax[5]=0; ax[6]=0; ax[7]=0;
    }
    short8 ah0 = mk_afrag(&hb[w][0][0][0], l15, g4);        // h0[t-1]
    f32x4 acc0[8];
    #pragma unroll
    for(int n=0;n<8;n++){
      f32x4 a; a[0]=bfr[0][n]; a[1]=bfr[0][n]; a[2]=bfr[0][n]; a[3]=bfr[0][n];
      a = __builtin_amdgcn_mfma_f32_16x16x32_bf16(ax,  wf[3][n], a, 0,0,0);
      a = __builtin_amdgcn_mfma_f32_16x16x32_bf16(ah0, wf[0][n], a, 0,0,0);
      acc0[n] = a;
    }
    #pragma unroll
    for(int half=0; half<2; half++)
      #pragma unroll
      for(int r=0;r<4;r++){
        float gi = acc0[0+half][r], gf = acc0[2+half][r];
        float gg = acc0[4+half][r], go = acc0[6+half][r];
        float cc = sigmf(gf)*c0[half*4+r] + sigmf(gi)*tanhf_(gg);
        c0[half*4+r] = cc;
        hb[w][0][g4*4+r][l15+16*half] = sigmf(go)*tanhf_(cc);
      }
    short8 ah0n = mk_afrag(&hb[w][0][0][0], l15, g4);       // h0[t]
    short8 ah1  = mk_afrag(&hb[w][1][0][0], l15, g4);       // h1[t-1]
    f32x4 acc1[8];
    #pragma unroll
    for(int n=0;n<8;n++){
      f32x4 a; a[0]=bfr[1][n]; a[1]=bfr[1][n]; a[2]=bfr[1][n]; a[3]=bfr[1][n];
      a = __builtin_amdgcn_mfma_f32_16x16x32_bf16(ah0n, wf[1][n], a, 0,0,0);
      a = __builtin_amdgcn_mfma_f32_16x16x32_bf16(ah1,  wf[2][n], a, 0,0,0);
      acc1[n] = a;
    }
    #pragma unroll
    for(int half=0; half<2; half++)
      #pragma unroll
      for(int r=0;r<4;r++){
        float gi = acc1[0+half][r], gf = acc1[2+half][r];
        float gg = acc1[4+half][r], go = acc1[6+half][r];
        float cc = sigmf(gf)*c1[half*4+r] + sigmf(gi)*tanhf_(gg);
        c1[half*4+r] = cc;
        hb[w][1][g4*4+r][l15+16*half] = sigmf(go)*tanhf_(cc);
      }
  }
  // epilogue: pos_p (fp32 from LDS h1) and vel
  if(l < 16){
    const int gs = base + l;
    #pragma unroll
    for(int d=0;d<3;d++){
      float a = fcb[d];
      #pragma unroll
      for(int u=0;u<32;u++) a += hb[w][1][l][u]*fcW[d*32+u];
      float pr = xT[(size_t)(315+d)*NSAMP + gs];
      pv[(size_t)d*NSAMP + gs]     = a;
      pv[(size_t)(3+d)*NSAMP + gs] = (a - pr)*10.f;
    }
  }
}

DI void allgather32(const float* mine8, float* full32, int q){
  const bool q1 = (q & 1) != 0;
  const bool q2 = (q & 2) != 0;
  float a[16];
  #pragma unroll
  for(int i=0;i<8;i++){
    float o = __shfl_xor(mine8[i], 1);
    a[i]    = q1 ? o : mine8[i];
    a[8+i]  = q1 ? mine8[i] : o;
  }
  #pragma unroll
  for(int i=0;i<16;i++){
    float o = __shfl_xor(a[i], 2);
    full32[i]    = q2 ? o : a[i];
    full32[16+i] = q2 ? a[i] : o;
  }
}
DI float qreduce(float v){
  v += __shfl_xor(v, 1);
  v += __shfl_xor(v, 2);
  return v;
}

// ---------- conv + FC tail: 4 threads per sample, 256 thr = 64 samples ----------
__global__ __launch_bounds__(256,4) void conv_kernel(Params p){
  const int tid  = threadIdx.x;
  const int q    = tid & 3;
  const int sloc = tid >> 2;
  const int b    = blockIdx.x*64 + sloc;
  const float* __restrict__ xb = p.xT;
  __shared__ float sbuf[64*103];
  float* my = &sbuf[sloc*103];
  const int J0    = q*8;
  const int cbase = q*26;
  const int ncol  = (q==3) ? 24 : 26;

  float pp[3], vel[3];
  #pragma unroll
  for(int d=0;d<3;d++){
    pp[d]  = p.pv[(size_t)d*NSAMP + b];
    vel[d] = p.pv[(size_t)(3+d)*NSAMP + b];
  }

  // conv pass 1: LN stats
  float s1 = 0.f, s2 = 0.f;
  {
    float u0[3],u1[3],u2[3],u3[3],u4[3];
    #pragma unroll
    for(int r=0;r<3;r++){
      int pc;
      pc = cbase-2; u0[r] = (pc>=0) ? ldcsi(xb,b,r,pc<0?0:pc) : 0.f;
      pc = cbase-1; u1[r] = (pc>=0) ? ldcsi(xb,b,r,pc<0?0:pc) : 0.f;
      u2[r] = ldcsi(xb,b,r,cbase);
      u3[r] = ldcsi(xb,b,r,cbase+1);
      u4[r] = ldcsi(xb,b,r,cbase+2);
    }
    #pragma unroll 2
    for(int i=0;i<26;i++){
      float msk = (q==3 && i>=24) ? 0.f : 1.f;
      #pragma unroll
      for(int o=0;o<4;o++){
        const float* Wo = &p.W2[o*15];
        float s = p.b2[o];
        #pragma unroll
        for(int r=0;r<3;r++)
          s += u0[r]*Wo[r*5+0]+u1[r]*Wo[r*5+1]+u2[r]*Wo[r*5+2]+u3[r]*Wo[r*5+3]+u4[r]*Wo[r*5+4];
        s1 += msk*s; s2 += msk*s*s;
      }
      int pnext = cbase + i + 3;
      #pragma unroll
      for(int r=0;r<3;r++){
        float nv = ldcsi(xb,b,r,pnext);
        nv = (pnext <= 101) ? nv : 0.f;
        u0[r]=u1[r]; u1[r]=u2[r]; u2[r]=u3[r]; u3[r]=u4[r]; u4[r]=nv;
      }
    }
  }
  float m2  = qreduce(s1)*(1.f/408.f);
  float va2 = qreduce(s2)*(1.f/408.f) - m2*m2;
  float rs2 = frsq(va2 + 1e-5f);

  // conv pass 2 + LN/relu + cv3
  float w3v[4];
  #pragma unroll
  for(int o=0;o<4;o++) w3v[o] = p.W3[o];
  float b3v = p.b3[0];
  float s31=0.f, s32=0.f;
  {
    float u0[3],u1[3],u2[3],u3[3],u4[3];
    #pragma unroll
    for(int r=0;r<3;r++){
      int pc;
      pc = cbase-2; u0[r] = (pc>=0) ? ldcsi(xb,b,r,pc<0?0:pc) : 0.f;
      pc = cbase-1; u1[r] = (pc>=0) ? ldcsi(xb,b,r,pc<0?0:pc) : 0.f;
      u2[r] = ldcsi(xb,b,r,cbase);
      u3[r] = ldcsi(xb,b,r,cbase+1);
      u4[r] = ldcsi(xb,b,r,cbase+2);
    }
    #pragma unroll 2
    for(int i=0;i<26;i++){
      const int w = cbase + i;
      float msk = (q==3 && i>=24) ? 0.f : 1.f;
      float o3 = b3v;
      #pragma unroll
      for(int o=0;o<4;o++){
        const float* Wo = &p.W2[o*15];
        float s = p.b2[o];
        #pragma unroll
        for(int r=0;r<3;r++)
          s += u0[r]*Wo[r*5+0]+u1[r]*Wo[r*5+1]+u2[r]*Wo[r*5+2]+u3[r]*Wo[r*5+3]+u4[r]*Wo[r*5+4];
        int wc = (w <= 101) ? w : 101;
        float nv = (s - m2)*rs2*p.g2[o*102+wc] + p.be2[o*102+wc];
        o3 += fmaxf(nv, 0.f)*w3v[o];
      }
      s31 += msk*o3; s32 += msk*o3*o3;
      if(i < ncol) my[w] = o3;
      int pnext = cbase + i + 3;
      #pragma unroll
      for(int r=0;r<3;r++){
        float nv = ldcsi(xb,b,r,pnext);
        nv = (pnext <= 101) ? nv : 0.f;
        u0[r]=u1[r]; u1[r]=u2[r]; u2[r]=u3[r]; u3[r]=u4[r]; u4[r]=nv;
      }
    }
  }
  float m3  = qreduce(s31)*(1.f/102.f);
  float va3 = qreduce(s32)*(1.f/102.f) - m3*m3;
  float rs3 = frsq(va3 + 1e-5f);

  // f1: 108 -> 32 (8 outputs/thread), LN, relu
  float a1[8];
  #pragma unroll
  for(int jj=0;jj<8;jj++) a1[jj] = p.b1f[J0+jj];
  #pragma unroll 2
  for(int w=0; w<102; ++w){
    float v = (my[w]-m3)*rs3*p.g3[w] + p.be3[w];
    v = fmaxf(v, 0.f);
    const float* wr = &p.w1ft[w*32+J0];
    #pragma unroll
    for(int jj=0;jj<8;jj++) a1[jj] += v * wr[jj];
  }
  #pragma unroll
  for(int d=0;d<3;d++){
    #pragma unroll
    for(int jj=0;jj<8;jj++){
      a1[jj] += pp[d]  * p.w1ft[(102+d)*32+J0+jj];
      a1[jj] += vel[d] * p.w1ft[(105+d)*32+J0+jj];
    }
  }
  {
    float s=0.f, qq=0.f;
    #pragma unroll
    for(int jj=0;jj<8;jj++){ s += a1[jj]; qq += a1[jj]*a1[jj]; }
    float m  = qreduce(s)*(1.f/32.f);
    float va = qreduce(qq)*(1.f/32.f) - m*m;
    float rs = frsq(va + 1e-5f);
    #pragma unroll
    for(int jj=0;jj<8;jj++)
      a1[jj] = fmaxf((a1[jj]-m)*rs*p.g1f[J0+jj] + p.be1f[J0+jj], 0.f);
  }

  // f2: 32 -> 32
  float a1f[32];
  allgather32(a1, a1f, q);
  float a2[8];
  #pragma unroll
  for(int jj=0;jj<8;jj++){
    const int j = J0 + jj;
    float a = p.b2f[j];
    #pragma unroll
    for(int k=0;k<32;k++) a += a1f[k]*p.W2f[j*32+k];
    a2[jj] = a;
  }
  {
    float s=0.f, qq=0.f;
    #pragma unroll
    for(int jj=0;jj<8;jj++){ s += a2[jj]; qq += a2[jj]*a2[jj]; }
    float m  = qreduce(s)*(1.f/32.f);
    float va = qreduce(qq)*(1.f/32.f) - m*m;
    float rs = frsq(va + 1e-5f);
    #pragma unroll
    for(int jj=0;jj<8;jj++)
      a2[jj] = fmaxf((a2[jj]-m)*rs*p.g2f[J0+jj] + p.be2f[J0+jj], 0.f);
  }

  // f3: 32 -> 102 (26 cols/thread), LN, sigmoid; pre-LN staged in my[]
  float a2f[32];
  allgather32(a2, a2f, q);
  float t1=0.f, t2=0.f;
  #pragma unroll
  for(int i=0;i<26;i++){
    const int w  = cbase + i;
    const int wc = (w <= 101) ? w : 101;
    float a = p.b3f[wc];
    #pragma unroll
    for(int j=0;j<32;j++) a += a2f[j]*p.W3f[wc*32+j];
    float msk = (q==3 && i>=24) ? 0.f : 1.f;
    t1 += msk*a; t2 += msk*a*a;
    if(i < ncol) my[w] = a;
  }
  float mf  = qreduce(t1)*(1.f/102.f);
  float vaf = qreduce(t2)*(1.f/102.f) - mf*mf;
  float rsf = frsq(vaf + 1e-5f);
  #pragma unroll
  for(int i=0;i<26;i++){
    const int w = cbase + i;
    if(i < ncol){
      float u = (my[w]-mf)*rsf*p.g3f[w] + p.be3f[w];
      my[w] = sigmf(u);
    }
  }
  __syncthreads();

  // coalesced float4 store: 6528 floats/block
  float* op = p.out + (size_t)blockIdx.x*6528;
  #pragma unroll 1
  for(int m=0;m<7;m++){
    int i4 = tid + 256*m;
    if(i4 < 1632){
      int i0 = i4*4;
      float4 v;
      #pragma unroll
      for(int e=0;e<4;e++){
        int idx = i0 + e;
        int sm = idx/102;
        int wd = idx - sm*102;
        ((float*)&v)[e] = sbuf[sm*103 + wd];
      }
      *reinterpret_cast<float4*>(op + i0) = v;
    }
  }
}

// ---------- AoS monolithic fallback (R1, proven) ----------
template<int IN>
DI void lstm_step(const float* __restrict__ Wih, const float* __restrict__ Whh,
                  const float* __restrict__ bih, const float* __restrict__ bhh,
                  const float* xin, const float* hin, float* c, float* hout){
  #pragma unroll
  for(int j=0;j<32;j++){
    float ai = bih[j]    + bhh[j];
    float af = bih[32+j] + bhh[32+j];
    float ag = bih[64+j] + bhh[64+j];
    float ao = bih[96+j] + bhh[96+j];
    #pragma unroll
    for(int k=0;k<IN;k++){
      float xv = xin[k];
      ai += xv*Wih[j*IN+k]; af += xv*Wih[(32+j)*IN+k];
      ag += xv*Wih[(64+j)*IN+k]; ao += xv*Wih[(96+j)*IN+k];
    }
    #pragma unroll
    for(int k=0;k<32;k++){
      float hv = hin[k];
      ai += hv*Whh[j*32+k]; af += hv*Whh[(32+j)*32+k];
      ag += hv*Whh[(64+j)*32+k]; ao += hv*Whh[(96+j)*32+k];
    }
    float cc = sigmf(af)*c[j] + sigmf(ai)*tanhf_(ag);
    c[j] = cc;
    hout[j] = sigmf(ao)*tanhf_(cc);
  }
}

__global__ __launch_bounds__(128,1) void csnet_mono(Params p){
  const int tid = threadIdx.x;
  const int b = blockIdx.x*128 + tid;
  const float* __restrict__ xr = p.x + (size_t)b*348;
  __shared__ float sbuf[128*103];
  float* my = &sbuf[tid*103];
  float h0[32], c0[32], h1[32], c1[32];
  #pragma unroll
  for(int j=0;j<32;j++){ h0[j]=0.f; c0[j]=0.f; h1[j]=0.f; c1[j]=0.f; }
  #pragma unroll 1
  for(int t=0;t<4;t++){
    float xt[3];
    #pragma unroll
    for(int d=0;d<3;d++) xt[d] = xr[220 + t*3 + d];
    float hA[32], hB[32];
    lstm_step<3 >(p.Wih0,p.Whh0,p.bih0,p.bhh0, xt, h0, c0, hA);
    lstm_step<32>(p.Wih1,p.Whh1,p.bih1,p.bhh1, hA, h1, c1, hB);
    #pragma unroll
    for(int j=0;j<32;j++){ h0[j]=hA[j]; h1[j]=hB[j]; }
  }
  float pp[3], vel[3];
  #pragma unroll
  for(int d=0;d<3;d++){
    float a = p.fcb[d];
    #pragma unroll
    for(int j=0;j<32;j++) a += h1[j]*p.fcW[d*32+j];
    pp[d]  = a;
    vel[d] = (a - xr[229+d])*10.f;
  }
  float s1 = 0.f, s2 = 0.f;
  for(int w=0; w<102; ++w){
    #pragma unroll
    for(int o=0;o<4;o++){
      float s = p.b2[o];
      #pragma unroll
      for(int r=0;r<3;r++)
        #pragma unroll
        for(int kk=0;kk<5;kk++){
          int c = w - 2 + kk;
          float v = (c>=0 && c<=101) ? xr[r*116 + 1 + (c<0?0:(c>101?101:c))] : 0.f;
          s += v*p.W2[o*15 + r*5 + kk];
        }
      s1 += s; s2 += s*s;
    }
  }
  float m2  = s1*(1.f/408.f);
  float rs2 = frsq(s2*(1.f/408.f) - m2*m2 + 1e-5f);
  float s31=0.f, s32=0.f;
  for(int w=0; w<102; ++w){
    float o3 = p.b3[0];
    #pragma unroll
    for(int o=0;o<4;o++){
      float s = p.b2[o];
      #pragma unroll
      for(int r=0;r<3;r++)
        #pragma unroll
        for(int kk=0;kk<5;kk++){
          int c = w - 2 + kk;
          float v = (c>=0 && c<=101) ? xr[r*116 + 1 + (c<0?0:(c>101?101:c))] : 0.f;
          s += v*p.W2[o*15 + r*5 + kk];
        }
      float nv = (s - m2)*rs2*p.g2[o*102+w] + p.be2[o*102+w];
      o3 += fmaxf(nv, 0.f)*p.W3[o];
    }
    s31 += o3; s32 += o3*o3;
    my[w] = o3;
  }
  float m3  = s31*(1.f/102.f);
  float rs3 = frsq(s32*(1.f/102.f) - m3*m3 + 1e-5f);
  float a1[32];
  #pragma unroll
  for(int j=0;j<32;j++) a1[j] = p.b1f[j];
  for(int w=0; w<102; ++w){
    float v = fmaxf((my[w]-m3)*rs3*p.g3[w] + p.be3[w], 0.f);
    #pragma unroll
    for(int j=0;j<32;j++) a1[j] += v*p.W1f[j*108+w];
  }
  #pragma unroll
  for(int d=0;d<3;d++)
    #pragma unroll
    for(int j=0;j<32;j++){
      a1[j] += pp[d]*p.W1f[j*108+102+d];
      a1[j] += vel[d]*p.W1f[j*108+105+d];
    }
  {
    float s=0.f,qq=0.f;
    #pragma unroll
    for(int j=0;j<32;j++){ s+=a1[j]; qq+=a1[j]*a1[j]; }
    float m=s*(1.f/32.f), rs=frsq(qq*(1.f/32.f)-m*m+1e-5f);
    #pragma unroll
    for(int j=0;j<32;j++) a1[j]=fmaxf((a1[j]-m)*rs*p.g1f[j]+p.be1f[j],0.f);
  }
  float a2[32];
  #pragma unroll
  for(int j=0;j<32;j++){
    float a = p.b2f[j];
    #pragma unroll
    for(int k=0;k<32;k++) a += a1[k]*p.W2f[j*32+k];
    a2[j]=a;
  }
  {
    float s=0.f,qq=0.f;
    #pragma unroll
    for(int j=0;j<32;j++){ s+=a2[j]; qq+=a2[j]*a2[j]; }
    float m=s*(1.f/32.f), rs=frsq(qq*(1.f/32.f)-m*m+1e-5f);
    #pragma unroll
    for(int j=0;j<32;j++) a2[j]=fmaxf((a2[j]-m)*rs*p.g2f[j]+p.be2f[j],0.f);
  }
  float t1=0.f,t2=0.f;
  for(int w=0;w<102;++w){
    float a = p.b3f[w];
    #pragma unroll
    for(int j=0;j<32;j++) a += a2[j]*p.W3f[w*32+j];
    t1+=a; t2+=a*a;
    my[w]=a;
  }
  float mf=t1*(1.f/102.f), rsf=frsq(t2*(1.f/102.f)-mf*mf+1e-5f);
  for(int w=0;w<102;++w) my[w]=sigmf((my[w]-mf)*rsf*p.g3f[w]+p.be3f[w]);
  __syncthreads();
  float* op = p.out + (size_t)blockIdx.x*13056;
  #pragma unroll 1
  for(int m=0;m<26;m++){
    int i4 = tid + 128*m;
    if(i4 < 3264){
      int i0=i4*4;
      float4 v;
      #pragma unroll
      for(int e=0;e<4;e++){
        int idx=i0+e; int sm=idx/102; int wd=idx-sm*102;
        ((float*)&v)[e]=sbuf[sm*103+wd];
      }
      *reinterpret_cast<float4*>(op+i0)=v;
    }
  }
}

extern "C" void kernel_launch(void* const* d_in, const int* in_sizes, int n_in,
                              void* d_out, int out_size, void* d_ws, size_t ws_size,
                              hipStream_t stream) {
  (void)in_sizes; (void)n_in; (void)out_size;
  Params p;
  p.x    = (const float*)d_in[0];
  p.Wih0 = (const float*)d_in[1];  p.Whh0 = (const float*)d_in[2];
  p.bih0 = (const float*)d_in[3];  p.bhh0 = (const float*)d_in[4];
  p.Wih1 = (const float*)d_in[5];  p.Whh1 = (const float*)d_in[6];
  p.bih1 = (const float*)d_in[7];  p.bhh1 = (const float*)d_in[8];
  p.fcW  = (const float*)d_in[9];  p.fcb  = (const float*)d_in[10];
  p.W2   = (const float*)d_in[11]; p.b2   = (const float*)d_in[12];
  p.g2   = (const float*)d_in[13]; p.be2  = (const float*)d_in[14];
  p.W3   = (const float*)d_in[15]; p.b3   = (const float*)d_in[16];
  p.g3   = (const float*)d_in[17]; p.be3  = (const float*)d_in[18];
  p.W1f  = (const float*)d_in[19]; p.b1f  = (const float*)d_in[20];
  p.g1f  = (const float*)d_in[21]; p.be1f = (const float*)d_in[22];
  p.W2f  = (const float*)d_in[23]; p.b2f  = (const float*)d_in[24];
  p.g2f  = (const float*)d_in[25]; p.be2f = (const float*)d_in[26];
  p.W3f  = (const float*)d_in[27]; p.b3f  = (const float*)d_in[28];
  p.g3f  = (const float*)d_in[29]; p.be3f = (const float*)d_in[30];
  p.out  = (float*)d_out;

  // ws layout (floats): xT[320*N] | w1ft[3456] | pv[6*N] | bsum[256] | frags(u16)
  const size_t XT_F   = (size_t)320*NSAMP;
  const size_t W1FT_F = 3456;
  const size_t PV_F   = (size_t)6*NSAMP;
  const size_t BS_F   = 256;
  const size_t FRAG_BYTES = (size_t)32*64*8*2;   // 4 mats x 8 tiles x 64 lanes x 8 bf16
  const size_t head_f = XT_F + W1FT_F + PV_F + BS_F;
  const size_t need = head_f*4 + FRAG_BYTES;

  if(ws_size >= need){
    float* xT   = (float*)d_ws;
    float* w1ft = xT + XT_F;
    float* pv   = w1ft + W1FT_F;
    float* bsum = pv + PV_F;
    unsigned short* frags = (unsigned short*)(bsum + BS_F);
    p.xT = xT; p.w1ft = w1ft; p.pv = pv;
    pack_kernel<<<NSAMP/64, 256, 0, stream>>>(p.x, xT, p.W1f, w1ft);
    prep_kernel<<<1, 256, 0, stream>>>(p.Whh0, p.Wih1, p.Whh1, p.Wih0,
                                       p.bih0, p.bhh0, p.bih1, p.bhh1,
                                       frags, bsum);
    lstm_kernel<<<NSAMP/64, 256, 0, stream>>>(xT, frags, bsum, p.fcW, p.fcb, pv);
    conv_kernel<<<NSAMP/64, 256, 0, stream>>>(p);
  } else {
    p.xT = nullptr; p.w1ft = nullptr; p.pv = nullptr;
    csnet_mono<<<NSAMP/128, 128, 0, stream>>>(p);
  }
}